// Round 1
// baseline (1987.714 us; speedup 1.0000x reference)
//
#include <hip/hip_runtime.h>

#define TT 40
#define NB 256
#define DD 2048

typedef __bf16 bf16x8 __attribute__((ext_vector_type(8)));
typedef float f32x4 __attribute__((ext_vector_type(4)));
typedef unsigned short u16;
typedef unsigned int u32;
typedef u16 u16x8 __attribute__((ext_vector_type(8)));

__device__ __forceinline__ u16 f2bf(float f) {
  u32 u = __builtin_bit_cast(u32, f);
  return (u16)((u + 0x7fffu + ((u >> 16) & 1u)) >> 16);
}
__device__ __forceinline__ float bf2f(u16 h) {
  return __builtin_bit_cast(float, ((u32)h) << 16);
}
__device__ __forceinline__ bf16x8 asbf(u16x8 v) { return __builtin_bit_cast(bf16x8, v); }

__device__ __forceinline__ float sigm(float x) { return 1.0f / (1.0f + __expf(-x)); }
__device__ __forceinline__ float tanh_(float x) {
  float e = __expf(-2.0f * fabsf(x));
  float t = (1.0f - e) / (1.0f + e);
  return copysignf(t, x);
}

__device__ __forceinline__ f32x4 mfma16(bf16x8 a, bf16x8 b, f32x4 c) {
  return __builtin_amdgcn_mfma_f32_16x16x32_bf16(a, b, c, 0, 0, 0);
}

// ---------------- weight prep: reorder W into A-fragment layout, bf16 ----------------
// A-frag for tile (kt, mt): lane l, elem j holds A[row = mt*16 + (l&15), k = kt*32 + (l>>4)*8 + j]
// row p is PERMUTED oc: oc = (p&3)*32 + ((p>>5)&3)*8 + ((p>>4)&1)*4 + ((p>>2)&3)
// K ordering: k = (ky*KK + kx)*64 + ic
__global__ void prep_weights(const float* __restrict__ W0, const float* __restrict__ W1,
                             u16* __restrict__ A0, u16* __restrict__ A1) {
  int tid = blockIdx.x * 256 + threadIdx.x;
  if (tid < 25600) {  // conv0: 50 ktiles * 8 mtiles * 64 lanes
    int lane = tid & 63;
    int kt = tid >> 9;
    int p = ((tid >> 6) & 7) * 16 + (lane & 15);
    int oc = (p & 3) * 32 + ((p >> 5) & 3) * 8 + ((p >> 4) & 1) * 4 + ((p >> 2) & 3);
    int kb = kt * 32 + (lane >> 4) * 8;
#pragma unroll
    for (int j = 0; j < 8; ++j) {
      int k = kb + j;
      int pos = k >> 6, ic = k & 63;
      int ky = pos / 5, kx = pos - ky * 5;
      A0[tid * 8 + j] = f2bf(W0[((oc * 64 + ic) * 5 + ky) * 5 + kx]);
    }
  } else if (tid < 25600 + 9216) {  // conv1: 18 ktiles * 8 * 64
    int t2 = tid - 25600;
    int lane = t2 & 63;
    int kt = t2 >> 9;
    int p = ((t2 >> 6) & 7) * 16 + (lane & 15);
    int oc = (p & 3) * 32 + ((p >> 5) & 3) * 8 + ((p >> 4) & 1) * 4 + ((p >> 2) & 3);
    int kb = kt * 32 + (lane >> 4) * 8;
#pragma unroll
    for (int j = 0; j < 8; ++j) {
      int k = kb + j;
      int pos = k >> 6, ic = k & 63;
      int ky = pos / 3, kx = pos - ky * 3;
      A1[t2 * 8 + j] = f2bf(W1[((oc * 64 + ic) * 3 + ky) * 3 + kx]);
    }
  }
}

// ---------------- conv inner loop ----------------
// img: LDS padded 12x12 image, layout idx = P*64 + (ic ^ ((P&7)<<3)), bf16.
// O^T[p=0..127, pixel=0..63]; wave w owns M-tiles 2w, 2w+1 (its 32 permuted rows).
template <int KK, int NKT, int SKB>
__device__ __forceinline__ void conv_loop(const u16* __restrict__ wsA, const u16* img,
                                          int w, int lane, f32x4 acc[2][4]) {
  const int ic0v = (lane >> 4) << 3;
  const int pb0 = ((lane & 15) >> 3) * 12 + (lane & 7);
  const bf16x8* A = (const bf16x8*)wsA;
  int aidx = 2 * w * 64 + lane;
  bf16x8 a0 = A[aidx];
  bf16x8 a1 = A[aidx + 64];
#pragma unroll
  for (int kt = 0; kt < NKT; ++kt) {
    bf16x8 na0 = a0, na1 = a1;
    if (kt + 1 < NKT) {  // 1-deep prefetch of next A-frags (global, L2-resident)
      na0 = A[aidx + 512];
      na1 = A[aidx + 576];
    }
    const int pos = kt >> 1, ih = kt & 1;
    const int ky = pos / KK, kx = pos - ky * KK;
    int Pb = pb0 + (ky * 12 + kx + SKB);
    int idx = Pb * 64 + ((ic0v ^ ((Pb & 7) << 3)) ^ (ih << 5));
    u16x8 b0v = *(const u16x8*)(img + idx);
    u16x8 b1v = *(const u16x8*)(img + idx + 1536);
    u16x8 b2v = *(const u16x8*)(img + idx + 3072);
    u16x8 b3v = *(const u16x8*)(img + idx + 4608);
    acc[0][0] = mfma16(a0, asbf(b0v), acc[0][0]);
    acc[1][0] = mfma16(a1, asbf(b0v), acc[1][0]);
    acc[0][1] = mfma16(a0, asbf(b1v), acc[0][1]);
    acc[1][1] = mfma16(a1, asbf(b1v), acc[1][1]);
    acc[0][2] = mfma16(a0, asbf(b2v), acc[0][2]);
    acc[1][2] = mfma16(a1, asbf(b2v), acc[1][2]);
    acc[0][3] = mfma16(a0, asbf(b3v), acc[0][3]);
    acc[1][3] = mfma16(a1, asbf(b3v), acc[1][3]);
    a0 = na0;
    a1 = na1;
    aidx += 512;
  }
}

// ---------------- main: one batch per block, full T loop ----------------
__global__ void __launch_bounds__(256, 1)
convlstm_main(const float* __restrict__ x, const float* __restrict__ b0g,
              const float* __restrict__ b1g, const u16* __restrict__ wsA0,
              const u16* __restrict__ wsA1, u16* __restrict__ buf,
              float* __restrict__ out) {
  alignas(16) __shared__ u16 imgA[9216];  // conv0 input: ch0-31 = x_t, ch32-63 = h0
  alignas(16) __shared__ u16 imgB[9216];  // conv1 input: ch0-31 = att, ch32-63 = h1
  __shared__ float sdots[64];
  __shared__ float swts[64];

  const int tid = threadIdx.x;
  const int b = blockIdx.x;
  const int lane = tid & 63;
  const int w = tid >> 6;
  const int h = lane >> 4;
  const int l15 = lane & 15;

  for (int i = tid; i < 9216; i += 256) {
    imgA[i] = 0;
    imgB[i] = 0;
  }

  float c0st[2][4] = {};
  float c1st[2][4] = {};
  float bi0[2][4], bi1[2][4];
  const int ch0 = 8 * w + h;  // + 4*mi gives this lane's channel
#pragma unroll
  for (int mi = 0; mi < 2; ++mi)
#pragma unroll
    for (int j = 0; j < 4; ++j) {
      bi0[mi][j] = b0g[j * 32 + ch0 + 4 * mi];
      bi1[mi][j] = b1g[j * 32 + ch0 + 4 * mi];
    }

  const int Pldx = ((lane >> 3) + 2) * 12 + (lane & 7) + 2;  // x-load pixel (px = lane)
  const int swx = (Pldx & 7) << 3;
  const int Pl0 = ((l15 >> 3) + 2) * 12 + (l15 & 7) + 2;  // h-write pixel base
  const int swh = (Pl0 & 7) << 3;
  const int chA = tid >> 3;                        // att write channel
  const int Pa0 = ((tid & 7) + 2) * 12 + 2;        // att write pixel row base

  __syncthreads();

  for (int t = 0; t < TT; ++t) {
    // ---- phase 1: stage x_t into imgA channels 0..31 ----
    const float* xp = x + (size_t)(t * NB + b) * DD;
#pragma unroll
    for (int i = 0; i < 8; ++i) {
      int c = i * 4 + w;
      imgA[Pldx * 64 + (c ^ swx)] = f2bf(xp[c * 64 + lane]);
    }
    __syncthreads();

    // ---- phase 2: conv0 + LSTM0 ----
    f32x4 acc[2][4];
    f32x4 zz = {0.f, 0.f, 0.f, 0.f};
#pragma unroll
    for (int mi = 0; mi < 2; ++mi)
#pragma unroll
      for (int nt = 0; nt < 4; ++nt) acc[mi][nt] = zz;
    conv_loop<5, 50, 0>(wsA0, imgA, w, lane, acc);
    __syncthreads();  // all imgA reads done before h0 rewrite

    u16* bufrow = buf + (size_t)(t * NB + b) * DD;
#pragma unroll
    for (int mi = 0; mi < 2; ++mi) {
      int ch = ch0 + 4 * mi;
#pragma unroll
      for (int nt = 0; nt < 4; ++nt) {
        float ig = acc[mi][nt][0] + bi0[mi][0];
        float fg = acc[mi][nt][1] + bi0[mi][1];
        float og = acc[mi][nt][2] + bi0[mi][2];
        float cg = acc[mi][nt][3] + bi0[mi][3];
        float cn = sigm(fg) * c0st[mi][nt] + sigm(ig) * tanh_(cg);
        float hn = sigm(og) * tanh_(cn);
        c0st[mi][nt] = cn;
        u16 hb = f2bf(hn);
        imgA[(Pl0 + 24 * nt) * 64 + ((32 + ch) ^ swh)] = hb;
        bufrow[ch * 64 + nt * 16 + l15] = hb;
      }
    }
    __syncthreads();  // buf[t] drained (vmcnt0) before dots read it

    // ---- phase 3: dots[t'] = flat . buf[t'] for t' <= t ----
    {
      const u16x8* rowT = (const u16x8*)(buf + (size_t)(t * NB + b) * DD);
      for (int tp = w; tp <= t; tp += 4) {
        const u16x8* rowP = (const u16x8*)(buf + (size_t)(tp * NB + b) * DD);
        float s = 0.f;
#pragma unroll
        for (int i = 0; i < 4; ++i) {
          u16x8 fv = rowT[i * 64 + lane];
          u16x8 pv = rowP[i * 64 + lane];
#pragma unroll
          for (int j = 0; j < 8; ++j) s += bf2f(fv[j]) * bf2f(pv[j]);
        }
#pragma unroll
        for (int off = 32; off; off >>= 1) s += __shfl_xor(s, off, 64);
        if (lane == 0) sdots[tp] = s;
      }
    }
    __syncthreads();

    // ---- phase 4: softmax over t'<=t (wave 0) ----
    if (w == 0) {
      float v = (lane <= t) ? sdots[lane] : -3.0e38f;
      float m = v;
#pragma unroll
      for (int off = 32; off; off >>= 1) m = fmaxf(m, __shfl_xor(m, off, 64));
      float e = (lane <= t) ? __expf(v - m) : 0.f;
      float ss = e;
#pragma unroll
      for (int off = 32; off; off >>= 1) ss += __shfl_xor(ss, off, 64);
      swts[lane] = e / ss;
    }
    __syncthreads();

    // ---- phase 5: att = sum_t' w[t'] * buf[t'] -> imgB channels 0..31 ----
    {
      float av[8] = {0.f, 0.f, 0.f, 0.f, 0.f, 0.f, 0.f, 0.f};
      const u16x8* bv = (const u16x8*)buf;
      size_t cb = (size_t)b * 256 + tid;
      for (int tp = 0; tp <= t; ++tp) {
        float wt = swts[tp];
        u16x8 v = bv[cb + (size_t)tp * (NB * 256)];
#pragma unroll
        for (int j = 0; j < 8; ++j) av[j] = fmaf(wt, bf2f(v[j]), av[j]);
      }
#pragma unroll
      for (int j = 0; j < 8; ++j) {
        int P = Pa0 + j;
        imgB[P * 64 + (chA ^ ((P & 7) << 3))] = f2bf(av[j]);
      }
    }
    __syncthreads();

    // ---- phase 6: conv1 ----
#pragma unroll
    for (int mi = 0; mi < 2; ++mi)
#pragma unroll
      for (int nt = 0; nt < 4; ++nt) acc[mi][nt] = zz;
    conv_loop<3, 18, 13>(wsA1, imgB, w, lane, acc);
    __syncthreads();

    // ---- phase 7: LSTM1 + output ----
    float* outrow = out + (size_t)(t * NB + b) * DD;
#pragma unroll
    for (int mi = 0; mi < 2; ++mi) {
      int ch = ch0 + 4 * mi;
#pragma unroll
      for (int nt = 0; nt < 4; ++nt) {
        float ig = acc[mi][nt][0] + bi1[mi][0];
        float fg = acc[mi][nt][1] + bi1[mi][1];
        float og = acc[mi][nt][2] + bi1[mi][2];
        float cg = acc[mi][nt][3] + bi1[mi][3];
        float cn = sigm(fg) * c1st[mi][nt] + sigm(ig) * tanh_(cg);
        float hn = sigm(og) * tanh_(cn);
        c1st[mi][nt] = cn;
        imgB[(Pl0 + 24 * nt) * 64 + ((32 + ch) ^ swh)] = f2bf(hn);
        outrow[ch * 64 + nt * 16 + l15] = hn;
      }
    }
    __syncthreads();
  }
}

extern "C" void kernel_launch(void* const* d_in, const int* in_sizes, int n_in,
                              void* d_out, int out_size, void* d_ws, size_t ws_size,
                              hipStream_t stream) {
  const float* x = (const float*)d_in[0];
  const float* W0 = (const float*)d_in[1];
  const float* b0 = (const float*)d_in[2];
  const float* W1 = (const float*)d_in[3];
  const float* b1 = (const float*)d_in[4];
  float* out = (float*)d_out;

  u16* A0 = (u16*)d_ws;                         // 204800 bf16 = 400 KB
  u16* A1 = A0 + 204800;                        // 73728 bf16 = 144 KB
  u16* buf = (u16*)((char*)d_ws + (1 << 20));   // h0-history, 40*256*2048 bf16 = 40 MB

  prep_weights<<<136, 256, 0, stream>>>(W0, W1, A0, A1);
  convlstm_main<<<256, 256, 0, stream>>>(x, b0, b1, A0, A1, buf, out);
}

// Round 2
// 1777.090 us; speedup vs baseline: 1.1185x; 1.1185x over previous
//
#include <hip/hip_runtime.h>

#define TT 40
#define NB 256
#define DD 2048
#define HISTL 28  // history rows kept in LDS; rows >= HISTL live in global ws

typedef __bf16 bf16x8 __attribute__((ext_vector_type(8)));
typedef float f32x4 __attribute__((ext_vector_type(4)));
typedef unsigned short u16;
typedef unsigned int u32;
typedef u16 u16x8 __attribute__((ext_vector_type(8)));

__device__ __forceinline__ u16 f2bf(float f) {
  u32 u = __builtin_bit_cast(u32, f);
  return (u16)((u + 0x7fffu + ((u >> 16) & 1u)) >> 16);
}
__device__ __forceinline__ float bf2f(u16 h) {
  return __builtin_bit_cast(float, ((u32)h) << 16);
}
__device__ __forceinline__ bf16x8 asbf(u16x8 v) { return __builtin_bit_cast(bf16x8, v); }

__device__ __forceinline__ float sigm(float x) { return 1.0f / (1.0f + __expf(-x)); }
__device__ __forceinline__ float tanh_(float x) {
  float e = __expf(-2.0f * fabsf(x));
  float t = (1.0f - e) / (1.0f + e);
  return copysignf(t, x);
}

__device__ __forceinline__ f32x4 mfma16(bf16x8 a, bf16x8 b, f32x4 c) {
  return __builtin_amdgcn_mfma_f32_16x16x32_bf16(a, b, c, 0, 0, 0);
}

// ---------------- weight prep: reorder W into A-fragment layout, bf16 ----------------
// A-frag for tile (kt, mt): lane l, elem j holds A[row = mt*16 + (l&15), k = kt*32 + (l>>4)*8 + j]
// row p is PERMUTED oc: oc = (p&3)*32 + ((p>>5)&3)*8 + ((p>>4)&1)*4 + ((p>>2)&3)
// K ordering: k = (ky*KK + kx)*64 + ic
__global__ void prep_weights(const float* __restrict__ W0, const float* __restrict__ W1,
                             u16* __restrict__ A0, u16* __restrict__ A1) {
  int tid = blockIdx.x * 256 + threadIdx.x;
  if (tid < 25600) {  // conv0: 50 ktiles * 8 mtiles * 64 lanes
    int lane = tid & 63;
    int kt = tid >> 9;
    int p = ((tid >> 6) & 7) * 16 + (lane & 15);
    int oc = (p & 3) * 32 + ((p >> 5) & 3) * 8 + ((p >> 4) & 1) * 4 + ((p >> 2) & 3);
    int kb = kt * 32 + (lane >> 4) * 8;
#pragma unroll
    for (int j = 0; j < 8; ++j) {
      int k = kb + j;
      int pos = k >> 6, ic = k & 63;
      int ky = pos / 5, kx = pos - ky * 5;
      A0[tid * 8 + j] = f2bf(W0[((oc * 64 + ic) * 5 + ky) * 5 + kx]);
    }
  } else if (tid < 25600 + 9216) {  // conv1: 18 ktiles * 8 * 64
    int t2 = tid - 25600;
    int lane = t2 & 63;
    int kt = t2 >> 9;
    int p = ((t2 >> 6) & 7) * 16 + (lane & 15);
    int oc = (p & 3) * 32 + ((p >> 5) & 3) * 8 + ((p >> 4) & 1) * 4 + ((p >> 2) & 3);
    int kb = kt * 32 + (lane >> 4) * 8;
#pragma unroll
    for (int j = 0; j < 8; ++j) {
      int k = kb + j;
      int pos = k >> 6, ic = k & 63;
      int ky = pos / 3, kx = pos - ky * 3;
      A1[t2 * 8 + j] = f2bf(W1[((oc * 64 + ic) * 3 + ky) * 3 + kx]);
    }
  }
}

// ---------------- conv inner loop ----------------
// img: LDS padded 12x12 image, layout idx = P*64 + (ic ^ ((P&7)<<3)), bf16.
// O^T[p=0..127, pixel=0..63]; wave w owns M-tiles 2w, 2w+1 (its 32 permuted rows).
template <int KK, int NKT, int SKB>
__device__ __forceinline__ void conv_loop(const u16* __restrict__ wsA, const u16* img,
                                          int w, int lane, f32x4 acc[2][4]) {
  const int ic0v = (lane >> 4) << 3;
  const int pb0 = ((lane & 15) >> 3) * 12 + (lane & 7);
  const bf16x8* A = (const bf16x8*)wsA;
  int aidx = 2 * w * 64 + lane;
  bf16x8 a0 = A[aidx];
  bf16x8 a1 = A[aidx + 64];
#pragma unroll
  for (int kt = 0; kt < NKT; ++kt) {
    bf16x8 na0 = a0, na1 = a1;
    if (kt + 1 < NKT) {  // 1-deep prefetch of next A-frags (global, L2-resident)
      na0 = A[aidx + 512];
      na1 = A[aidx + 576];
    }
    const int pos = kt >> 1, ih = kt & 1;
    const int ky = pos / KK, kx = pos - ky * KK;
    int Pb = pb0 + (ky * 12 + kx + SKB);
    int idx = Pb * 64 + ((ic0v ^ ((Pb & 7) << 3)) ^ (ih << 5));
    u16x8 b0v = *(const u16x8*)(img + idx);
    u16x8 b1v = *(const u16x8*)(img + idx + 1536);
    u16x8 b2v = *(const u16x8*)(img + idx + 3072);
    u16x8 b3v = *(const u16x8*)(img + idx + 4608);
    acc[0][0] = mfma16(a0, asbf(b0v), acc[0][0]);
    acc[1][0] = mfma16(a1, asbf(b0v), acc[1][0]);
    acc[0][1] = mfma16(a0, asbf(b1v), acc[0][1]);
    acc[1][1] = mfma16(a1, asbf(b1v), acc[1][1]);
    acc[0][2] = mfma16(a0, asbf(b2v), acc[0][2]);
    acc[1][2] = mfma16(a1, asbf(b2v), acc[1][2]);
    acc[0][3] = mfma16(a0, asbf(b3v), acc[0][3]);
    acc[1][3] = mfma16(a1, asbf(b3v), acc[1][3]);
    a0 = na0;
    a1 = na1;
    aidx += 512;
  }
}

// ---------------- main: one batch per block, full T loop ----------------
__global__ void __launch_bounds__(256, 1)
convlstm_main(const float* __restrict__ x, const float* __restrict__ b0g,
              const float* __restrict__ b1g, const u16* __restrict__ wsA0,
              const u16* __restrict__ wsA1, u16* __restrict__ buf,
              float* __restrict__ out) {
  alignas(16) __shared__ u16 imgA[9216];        // conv0 input: ch0-31 = x_t, ch32-63 = h0
  alignas(16) __shared__ u16 imgB[9216];        // conv1 input: ch0-31 = att, ch32-63 = h1
  alignas(16) __shared__ u16 hist[HISTL * DD];  // h0-history rows 0..HISTL-1 (112 KB)
  __shared__ float sdots[64];
  __shared__ float swts[64];

  const int tid = threadIdx.x;
  const int b = blockIdx.x;
  const int lane = tid & 63;
  const int w = tid >> 6;
  const int h = lane >> 4;
  const int l15 = lane & 15;

  for (int i = tid; i < 9216; i += 256) {
    imgA[i] = 0;
    imgB[i] = 0;
  }

  float c0st[2][4] = {};
  float c1st[2][4] = {};
  float bi0[2][4], bi1[2][4];
  const int ch0 = 8 * w + h;  // + 4*mi gives this lane's channel
#pragma unroll
  for (int mi = 0; mi < 2; ++mi)
#pragma unroll
    for (int j = 0; j < 4; ++j) {
      bi0[mi][j] = b0g[j * 32 + ch0 + 4 * mi];
      bi1[mi][j] = b1g[j * 32 + ch0 + 4 * mi];
    }

  const int Pldx = ((lane >> 3) + 2) * 12 + (lane & 7) + 2;  // x-load pixel (px = lane)
  const int swx = (Pldx & 7) << 3;
  const int Pl0 = ((l15 >> 3) + 2) * 12 + (l15 & 7) + 2;  // h-write pixel base
  const int swh = (Pl0 & 7) << 3;
  const int Pa0 = ((tid & 7) + 2) * 12 + 2;  // att write pixel row base (ch = tid>>3)

  __syncthreads();

  for (int t = 0; t < TT; ++t) {
    // ---- phase 1: stage x_t into imgA channels 0..31 ----
    const float* xp = x + (size_t)(t * NB + b) * DD;
#pragma unroll
    for (int i = 0; i < 8; ++i) {
      int c = i * 4 + w;
      imgA[Pldx * 64 + (c ^ swx)] = f2bf(xp[c * 64 + lane]);
    }
    __syncthreads();

    // ---- phase 2: conv0 + LSTM0 ----
    f32x4 acc[2][4];
    f32x4 zz = {0.f, 0.f, 0.f, 0.f};
#pragma unroll
    for (int mi = 0; mi < 2; ++mi)
#pragma unroll
      for (int nt = 0; nt < 4; ++nt) acc[mi][nt] = zz;
    conv_loop<5, 50, 0>(wsA0, imgA, w, lane, acc);
    __syncthreads();  // all imgA reads done before h0 rewrite

    u16* bufrow = buf + (size_t)(t * NB + b) * DD;  // used only when t >= HISTL
#pragma unroll
    for (int mi = 0; mi < 2; ++mi) {
      int ch = ch0 + 4 * mi;
#pragma unroll
      for (int nt = 0; nt < 4; ++nt) {
        float ig = acc[mi][nt][0] + bi0[mi][0];
        float fg = acc[mi][nt][1] + bi0[mi][1];
        float og = acc[mi][nt][2] + bi0[mi][2];
        float cg = acc[mi][nt][3] + bi0[mi][3];
        float cn = sigm(fg) * c0st[mi][nt] + sigm(ig) * tanh_(cg);
        float hn = sigm(og) * tanh_(cn);
        c0st[mi][nt] = cn;
        u16 hb = f2bf(hn);
        imgA[(Pl0 + 24 * nt) * 64 + ((32 + ch) ^ swh)] = hb;
        int d = ch * 64 + nt * 16 + l15;
        if (t < HISTL)
          hist[t * DD + d] = hb;
        else
          bufrow[d] = hb;
      }
    }
    __syncthreads();  // hist/buf row t visible before dots reads it

    // ---- phase 3: dots[t'] = flat . hist[t'] for t' <= t (wave-striped tp) ----
    {
      u16x8 fv[4];  // flat (= hist row t), loop-invariant: hoist
      if (t < HISTL) {
        const u16x8* rowT = (const u16x8*)&hist[t * DD];
#pragma unroll
        for (int i = 0; i < 4; ++i) fv[i] = rowT[i * 64 + lane];
      } else {
        const u16x8* rowT = (const u16x8*)bufrow;
#pragma unroll
        for (int i = 0; i < 4; ++i) fv[i] = rowT[i * 64 + lane];
      }
      int tp = w;
      for (; tp < HISTL && tp <= t; tp += 4) {  // LDS rows
        const u16x8* rowP = (const u16x8*)&hist[tp * DD];
        float s = 0.f;
#pragma unroll
        for (int i = 0; i < 4; ++i) {
          u16x8 pv = rowP[i * 64 + lane];
#pragma unroll
          for (int j = 0; j < 8; ++j) s += bf2f(fv[i][j]) * bf2f(pv[j]);
        }
#pragma unroll
        for (int off = 32; off; off >>= 1) s += __shfl_xor(s, off, 64);
        if (lane == 0) sdots[tp] = s;
      }
      for (; tp <= t; tp += 4) {  // global rows
        const u16x8* rowP = (const u16x8*)(buf + (size_t)(tp * NB + b) * DD);
        float s = 0.f;
#pragma unroll
        for (int i = 0; i < 4; ++i) {
          u16x8 pv = rowP[i * 64 + lane];
#pragma unroll
          for (int j = 0; j < 8; ++j) s += bf2f(fv[i][j]) * bf2f(pv[j]);
        }
#pragma unroll
        for (int off = 32; off; off >>= 1) s += __shfl_xor(s, off, 64);
        if (lane == 0) sdots[tp] = s;
      }
    }
    __syncthreads();

    // ---- phase 4: softmax over t'<=t (wave 0) ----
    if (w == 0) {
      float v = (lane <= t) ? sdots[lane] : -3.0e38f;
      float m = v;
#pragma unroll
      for (int off = 32; off; off >>= 1) m = fmaxf(m, __shfl_xor(m, off, 64));
      float e = (lane <= t) ? __expf(v - m) : 0.f;
      float ss = e;
#pragma unroll
      for (int off = 32; off; off >>= 1) ss += __shfl_xor(ss, off, 64);
      swts[lane] = e / ss;
    }
    __syncthreads();

    // ---- phase 5: att = sum_t' w[t'] * hist[t'] -> imgB channels 0..31 ----
    {
      float av[8] = {0.f, 0.f, 0.f, 0.f, 0.f, 0.f, 0.f, 0.f};
      const int e8 = tid * 8;  // this thread's d-slice: 8 consecutive elems
      int tp = 0;
      for (; tp < HISTL && tp <= t; ++tp) {  // LDS rows
        float wt = swts[tp];
        u16x8 v = *(const u16x8*)&hist[tp * DD + e8];
#pragma unroll
        for (int j = 0; j < 8; ++j) av[j] = fmaf(wt, bf2f(v[j]), av[j]);
      }
      for (; tp <= t; ++tp) {  // global rows
        float wt = swts[tp];
        u16x8 v = *(const u16x8*)(buf + (size_t)(tp * NB + b) * DD + e8);
#pragma unroll
        for (int j = 0; j < 8; ++j) av[j] = fmaf(wt, bf2f(v[j]), av[j]);
      }
#pragma unroll
      for (int j = 0; j < 8; ++j) {
        int P = Pa0 + j;
        imgB[P * 64 + ((tid >> 3) ^ ((P & 7) << 3))] = f2bf(av[j]);
      }
    }
    __syncthreads();

    // ---- phase 6: conv1 ----
#pragma unroll
    for (int mi = 0; mi < 2; ++mi)
#pragma unroll
      for (int nt = 0; nt < 4; ++nt) acc[mi][nt] = zz;
    conv_loop<3, 18, 13>(wsA1, imgB, w, lane, acc);
    __syncthreads();

    // ---- phase 7: LSTM1 + output ----
    float* outrow = out + (size_t)(t * NB + b) * DD;
#pragma unroll
    for (int mi = 0; mi < 2; ++mi) {
      int ch = ch0 + 4 * mi;
#pragma unroll
      for (int nt = 0; nt < 4; ++nt) {
        float ig = acc[mi][nt][0] + bi1[mi][0];
        float fg = acc[mi][nt][1] + bi1[mi][1];
        float og = acc[mi][nt][2] + bi1[mi][2];
        float cg = acc[mi][nt][3] + bi1[mi][3];
        float cn = sigm(fg) * c1st[mi][nt] + sigm(ig) * tanh_(cg);
        float hn = sigm(og) * tanh_(cn);
        c1st[mi][nt] = cn;
        imgB[(Pl0 + 24 * nt) * 64 + ((32 + ch) ^ swh)] = f2bf(hn);
        outrow[ch * 64 + nt * 16 + l15] = hn;
      }
    }
    __syncthreads();
  }
}

extern "C" void kernel_launch(void* const* d_in, const int* in_sizes, int n_in,
                              void* d_out, int out_size, void* d_ws, size_t ws_size,
                              hipStream_t stream) {
  const float* x = (const float*)d_in[0];
  const float* W0 = (const float*)d_in[1];
  const float* b0 = (const float*)d_in[2];
  const float* W1 = (const float*)d_in[3];
  const float* b1 = (const float*)d_in[4];
  float* out = (float*)d_out;

  u16* A0 = (u16*)d_ws;                        // 204800 bf16 = 400 KB
  u16* A1 = A0 + 204800;                       // 73728 bf16 = 144 KB
  u16* buf = (u16*)((char*)d_ws + (1 << 20));  // h0-history spill rows (t >= HISTL)

  prep_weights<<<136, 256, 0, stream>>>(W0, W1, A0, A1);
  convlstm_main<<<256, 256, 0, stream>>>(x, b0, b1, A0, A1, buf, out);
}

// Round 3
// 1490.764 us; speedup vs baseline: 1.3334x; 1.1921x over previous
//
#include <hip/hip_runtime.h>

#define TT 40
#define NB 256
#define DD 2048
#define HISTL 28  // history rows kept in LDS; rows >= HISTL live in global ws

typedef __bf16 bf16x8 __attribute__((ext_vector_type(8)));
typedef float f32x4 __attribute__((ext_vector_type(4)));
typedef unsigned short u16;
typedef unsigned int u32;
typedef u16 u16x8 __attribute__((ext_vector_type(8)));
typedef u16 u16x4 __attribute__((ext_vector_type(4)));

__device__ __forceinline__ u16 f2bf(float f) {
  u32 u = __builtin_bit_cast(u32, f);
  return (u16)((u + 0x7fffu + ((u >> 16) & 1u)) >> 16);
}
__device__ __forceinline__ float bf2f(u16 h) {
  return __builtin_bit_cast(float, ((u32)h) << 16);
}
__device__ __forceinline__ bf16x8 asbf(u16x8 v) { return __builtin_bit_cast(bf16x8, v); }

__device__ __forceinline__ float sigm(float x) { return 1.0f / (1.0f + __expf(-x)); }
__device__ __forceinline__ float tanh_(float x) {
  float e = __expf(-2.0f * fabsf(x));
  float t = (1.0f - e) / (1.0f + e);
  return copysignf(t, x);
}

__device__ __forceinline__ f32x4 mfma16(bf16x8 a, bf16x8 b, f32x4 c) {
  return __builtin_amdgcn_mfma_f32_16x16x32_bf16(a, b, c, 0, 0, 0);
}

// ---------------- weight prep: reorder W into A-fragment layout, bf16 ----------------
// A-frag for tile (kt, mt): lane l, elem j holds A[row = mt*16 + (l&15), k = kt*32 + (l>>4)*8 + j]
// row p is PERMUTED oc: oc = (p&3)*32 + ((p>>5)&3)*8 + ((p>>4)&1)*4 + ((p>>2)&3)
// K ordering: k = (ky*KK + kx)*64 + ic
__global__ void prep_weights(const float* __restrict__ W0, const float* __restrict__ W1,
                             u16* __restrict__ A0, u16* __restrict__ A1) {
  int tid = blockIdx.x * 256 + threadIdx.x;
  if (tid < 25600) {  // conv0: 50 ktiles * 8 mtiles * 64 lanes
    int lane = tid & 63;
    int kt = tid >> 9;
    int p = ((tid >> 6) & 7) * 16 + (lane & 15);
    int oc = (p & 3) * 32 + ((p >> 5) & 3) * 8 + ((p >> 4) & 1) * 4 + ((p >> 2) & 3);
    int kb = kt * 32 + (lane >> 4) * 8;
#pragma unroll
    for (int j = 0; j < 8; ++j) {
      int k = kb + j;
      int pos = k >> 6, ic = k & 63;
      int ky = pos / 5, kx = pos - ky * 5;
      A0[tid * 8 + j] = f2bf(W0[((oc * 64 + ic) * 5 + ky) * 5 + kx]);
    }
  } else if (tid < 25600 + 9216) {  // conv1: 18 ktiles * 8 * 64
    int t2 = tid - 25600;
    int lane = t2 & 63;
    int kt = t2 >> 9;
    int p = ((t2 >> 6) & 7) * 16 + (lane & 15);
    int oc = (p & 3) * 32 + ((p >> 5) & 3) * 8 + ((p >> 4) & 1) * 4 + ((p >> 2) & 3);
    int kb = kt * 32 + (lane >> 4) * 8;
#pragma unroll
    for (int j = 0; j < 8; ++j) {
      int k = kb + j;
      int pos = k >> 6, ic = k & 63;
      int ky = pos / 3, kx = pos - ky * 3;
      A1[t2 * 8 + j] = f2bf(W1[((oc * 64 + ic) * 3 + ky) * 3 + kx]);
    }
  }
}

// ---------------- conv inner loop (8 waves: wave w owns M-tile w) ----------------
// img: LDS padded 12x12 image, layout idx = P*64 + (ic ^ ((P&7)<<3)), bf16.
// 2-deep register prefetch ring on the A-fragments (global, L2-resident).
template <int KK, int NKT, int SKB>
__device__ __forceinline__ void conv_loop(const u16* __restrict__ wsA, const u16* img,
                                          int w, int lane, f32x4 acc[4]) {
  const int ic0v = (lane >> 4) << 3;
  const int pb0 = ((lane & 15) >> 3) * 12 + (lane & 7);
  const bf16x8* A = (const bf16x8*)wsA;
  int aidx = w * 64 + lane;
  bf16x8 a0 = A[aidx];
  bf16x8 a1 = A[aidx + 512];
#pragma unroll
  for (int kt = 0; kt < NKT; ++kt) {
    bf16x8 nx = a1;
    if (kt + 2 < NKT) nx = A[aidx + 1024];
    const int pos = kt >> 1, ih = kt & 1;
    const int ky = pos / KK, kx = pos - ky * KK;
    const int Pb = pb0 + (ky * 12 + kx + SKB);
    const int idx = Pb * 64 + ((ic0v ^ ((Pb & 7) << 3)) ^ (ih << 5));
    u16x8 b0v = *(const u16x8*)(img + idx);
    u16x8 b1v = *(const u16x8*)(img + idx + 1536);
    u16x8 b2v = *(const u16x8*)(img + idx + 3072);
    u16x8 b3v = *(const u16x8*)(img + idx + 4608);
    acc[0] = mfma16(a0, asbf(b0v), acc[0]);
    acc[1] = mfma16(a0, asbf(b1v), acc[1]);
    acc[2] = mfma16(a0, asbf(b2v), acc[2]);
    acc[3] = mfma16(a0, asbf(b3v), acc[3]);
    a0 = a1;
    a1 = nx;
    aidx += 512;
  }
}

__device__ __forceinline__ int imin(int a, int b) { return a < b ? a : b; }

// ---------------- main: one batch per block, 512 threads, full T loop ----------------
__global__ void __launch_bounds__(512, 1)
convlstm_main(const float* __restrict__ x, const float* __restrict__ b0g,
              const float* __restrict__ b1g, const u16* __restrict__ wsA0,
              const u16* __restrict__ wsA1, u16* __restrict__ buf,
              float* __restrict__ out) {
  alignas(16) __shared__ u16 imgA[9216];        // conv0 input: ch0-31 = x_t, ch32-63 = h0
  alignas(16) __shared__ u16 imgB[9216];        // conv1 input: ch0-31 = att, ch32-63 = h1
  alignas(16) __shared__ u16 hist[HISTL * DD];  // h0-history rows 0..HISTL-1 (112 KB)
  alignas(16) __shared__ u16 curr[DD];          // flat_t (current h0 row)
  __shared__ float sdots[64];
  __shared__ float swts[64];

  const int tid = threadIdx.x;
  const int b = blockIdx.x;
  const int lane = tid & 63;
  const int w = tid >> 6;
  const int h = lane >> 4;
  const int l15 = lane & 15;

  for (int i = tid; i < 9216; i += 512) {
    imgA[i] = 0;
    imgB[i] = 0;
  }

  float c0st[4] = {};
  float c1st[4] = {};
  float bi0[4], bi1[4];
  const int ch = ((w >> 1) & 3) * 8 + (w & 1) * 4 + h;  // this lane's conv-output channel
#pragma unroll
  for (int j = 0; j < 4; ++j) {
    bi0[j] = b0g[j * 32 + ch];
    bi1[j] = b1g[j * 32 + ch];
  }

  const int Pldx = ((lane >> 3) + 2) * 12 + (lane & 7) + 2;  // x-load pixel (px = lane)
  const int swx = (Pldx & 7) << 3;
  const int Pl0 = ((l15 >> 3) + 2) * 12 + (l15 & 7) + 2;  // h-write pixel base
  const int swh = (Pl0 & 7) << 3;
  const int e4 = tid * 4;                         // att: this thread's 4 d-elems
  const int chAtt = tid >> 4;                     // att write channel
  const int pix0 = (tid & 15) * 4;                // att write pixel base (py const over j)
  const int PaB = ((pix0 >> 3) + 2) * 12 + (pix0 & 7) + 2;

  // preload x registers for t=0
  float xr[4];
  {
    const float* xp = x + (size_t)b * DD;
#pragma unroll
    for (int i = 0; i < 4; ++i) xr[i] = xp[(i * 8 + w) * 64 + lane];
  }

  __syncthreads();

  for (int t = 0; t < TT; ++t) {
    // ---- phase 1: stage x_t (preloaded regs) into imgA channels 0..31 ----
#pragma unroll
    for (int i = 0; i < 4; ++i) {
      int c = i * 8 + w;
      imgA[Pldx * 64 + (c ^ swx)] = f2bf(xr[i]);
    }
    __syncthreads();

    // issue x loads for t+1 (latency hidden under conv0)
    if (t + 1 < TT) {
      const float* xp = x + (size_t)((t + 1) * NB + b) * DD;
#pragma unroll
      for (int i = 0; i < 4; ++i) xr[i] = xp[(i * 8 + w) * 64 + lane];
    }

    // ---- phase 2: conv0 + LSTM0 ----
    f32x4 acc[4];
    f32x4 zz = {0.f, 0.f, 0.f, 0.f};
#pragma unroll
    for (int nt = 0; nt < 4; ++nt) acc[nt] = zz;
    conv_loop<5, 50, 0>(wsA0, imgA, w, lane, acc);
    __syncthreads();  // all imgA reads done before h0 rewrite

    u16* bufrow = buf + (size_t)(t * NB + b) * DD;  // used only when t >= HISTL
#pragma unroll
    for (int nt = 0; nt < 4; ++nt) {
      float ig = acc[nt][0] + bi0[0];
      float fg = acc[nt][1] + bi0[1];
      float og = acc[nt][2] + bi0[2];
      float cg = acc[nt][3] + bi0[3];
      float cn = sigm(fg) * c0st[nt] + sigm(ig) * tanh_(cg);
      float hn = sigm(og) * tanh_(cn);
      c0st[nt] = cn;
      u16 hb = f2bf(hn);
      imgA[(Pl0 + 24 * nt) * 64 + ((32 + ch) ^ swh)] = hb;
      int d = ch * 64 + nt * 16 + l15;
      curr[d] = hb;
      if (t < HISTL)
        hist[t * DD + d] = hb;
      else
        bufrow[d] = hb;
    }
    __syncthreads();  // row t visible before dots reads it

    // ---- phase 3: dots[t'] = flat . hist[t'] for t' <= t (wave-striped tp) ----
    {
      u16x8 fv[4];  // flat_t, always from LDS curr
      {
        const u16x8* rowT = (const u16x8*)curr;
#pragma unroll
        for (int i = 0; i < 4; ++i) fv[i] = rowT[i * 64 + lane];
      }
      int tp = w;
      for (; tp <= t && tp < HISTL; tp += 8) {  // LDS rows
        const u16x8* rowP = (const u16x8*)&hist[tp * DD];
        u16x8 p0 = rowP[lane], p1 = rowP[64 + lane], p2 = rowP[128 + lane], p3 = rowP[192 + lane];
        float s0 = 0.f, s1 = 0.f, s2 = 0.f, s3 = 0.f;
#pragma unroll
        for (int j = 0; j < 8; ++j) {
          s0 += bf2f(fv[0][j]) * bf2f(p0[j]);
          s1 += bf2f(fv[1][j]) * bf2f(p1[j]);
          s2 += bf2f(fv[2][j]) * bf2f(p2[j]);
          s3 += bf2f(fv[3][j]) * bf2f(p3[j]);
        }
        float s = (s0 + s1) + (s2 + s3);
#pragma unroll
        for (int off = 32; off; off >>= 1) s += __shfl_xor(s, off, 64);
        if (lane == 0) sdots[tp] = s;
      }
      for (; tp < t; tp += 8) {  // global rows HISTL..t-1
        const u16x8* rowP = (const u16x8*)(buf + (size_t)(tp * NB + b) * DD);
        u16x8 p0 = rowP[lane], p1 = rowP[64 + lane], p2 = rowP[128 + lane], p3 = rowP[192 + lane];
        float s0 = 0.f, s1 = 0.f, s2 = 0.f, s3 = 0.f;
#pragma unroll
        for (int j = 0; j < 8; ++j) {
          s0 += bf2f(fv[0][j]) * bf2f(p0[j]);
          s1 += bf2f(fv[1][j]) * bf2f(p1[j]);
          s2 += bf2f(fv[2][j]) * bf2f(p2[j]);
          s3 += bf2f(fv[3][j]) * bf2f(p3[j]);
        }
        float s = (s0 + s1) + (s2 + s3);
#pragma unroll
        for (int off = 32; off; off >>= 1) s += __shfl_xor(s, off, 64);
        if (lane == 0) sdots[tp] = s;
      }
      if (tp == t) {  // row t (only when t >= HISTL; else covered by LDS loop)
        float s0 = 0.f, s1 = 0.f, s2 = 0.f, s3 = 0.f;
#pragma unroll
        for (int j = 0; j < 8; ++j) {
          s0 += bf2f(fv[0][j]) * bf2f(fv[0][j]);
          s1 += bf2f(fv[1][j]) * bf2f(fv[1][j]);
          s2 += bf2f(fv[2][j]) * bf2f(fv[2][j]);
          s3 += bf2f(fv[3][j]) * bf2f(fv[3][j]);
        }
        float s = (s0 + s1) + (s2 + s3);
#pragma unroll
        for (int off = 32; off; off >>= 1) s += __shfl_xor(s, off, 64);
        if (lane == 0) sdots[tp] = s;
      }
    }
    __syncthreads();

    // ---- phase 4: softmax over t'<=t (wave 0) ----
    if (w == 0) {
      float v = (lane <= t) ? sdots[lane] : -3.0e38f;
      float m = v;
#pragma unroll
      for (int off = 32; off; off >>= 1) m = fmaxf(m, __shfl_xor(m, off, 64));
      float e = (lane <= t) ? __expf(v - m) : 0.f;
      float ss = e;
#pragma unroll
      for (int off = 32; off; off >>= 1) ss += __shfl_xor(ss, off, 64);
      swts[lane] = e / ss;
    }
    __syncthreads();

    // ---- phase 5: att = sum_t' w[t'] * hist[t'] -> imgB channels 0..31 ----
    {
      float av0 = 0.f, av1 = 0.f, av2 = 0.f, av3 = 0.f;
      const int lim = imin(t, HISTL);  // LDS rows [0, lim); row t handled from curr
      int tp = 0;
      for (; tp + 1 < lim; tp += 2) {  // 2-way unrolled LDS rows
        float wa = swts[tp], wb = swts[tp + 1];
        u16x4 va = *(const u16x4*)&hist[tp * DD + e4];
        u16x4 vb = *(const u16x4*)&hist[(tp + 1) * DD + e4];
        av0 = fmaf(wa, bf2f(va[0]), av0);
        av1 = fmaf(wa, bf2f(va[1]), av1);
        av2 = fmaf(wa, bf2f(va[2]), av2);
        av3 = fmaf(wa, bf2f(va[3]), av3);
        av0 = fmaf(wb, bf2f(vb[0]), av0);
        av1 = fmaf(wb, bf2f(vb[1]), av1);
        av2 = fmaf(wb, bf2f(vb[2]), av2);
        av3 = fmaf(wb, bf2f(vb[3]), av3);
      }
      if (tp < lim) {
        float wa = swts[tp];
        u16x4 va = *(const u16x4*)&hist[tp * DD + e4];
        av0 = fmaf(wa, bf2f(va[0]), av0);
        av1 = fmaf(wa, bf2f(va[1]), av1);
        av2 = fmaf(wa, bf2f(va[2]), av2);
        av3 = fmaf(wa, bf2f(va[3]), av3);
      }
      tp = HISTL;
      for (; tp + 1 < t; tp += 2) {  // 2-way unrolled global rows
        float wa = swts[tp], wb = swts[tp + 1];
        u16x4 va = *(const u16x4*)(buf + (size_t)(tp * NB + b) * DD + e4);
        u16x4 vb = *(const u16x4*)(buf + (size_t)((tp + 1) * NB + b) * DD + e4);
        av0 = fmaf(wa, bf2f(va[0]), av0);
        av1 = fmaf(wa, bf2f(va[1]), av1);
        av2 = fmaf(wa, bf2f(va[2]), av2);
        av3 = fmaf(wa, bf2f(va[3]), av3);
        av0 = fmaf(wb, bf2f(vb[0]), av0);
        av1 = fmaf(wb, bf2f(vb[1]), av1);
        av2 = fmaf(wb, bf2f(vb[2]), av2);
        av3 = fmaf(wb, bf2f(vb[3]), av3);
      }
      if (tp < t) {
        float wa = swts[tp];
        u16x4 va = *(const u16x4*)(buf + (size_t)(tp * NB + b) * DD + e4);
        av0 = fmaf(wa, bf2f(va[0]), av0);
        av1 = fmaf(wa, bf2f(va[1]), av1);
        av2 = fmaf(wa, bf2f(va[2]), av2);
        av3 = fmaf(wa, bf2f(va[3]), av3);
      }
      {  // row t from curr (LDS)
        float wa = swts[t];
        u16x4 va = *(const u16x4*)&curr[e4];
        av0 = fmaf(wa, bf2f(va[0]), av0);
        av1 = fmaf(wa, bf2f(va[1]), av1);
        av2 = fmaf(wa, bf2f(va[2]), av2);
        av3 = fmaf(wa, bf2f(va[3]), av3);
      }
      float av[4] = {av0, av1, av2, av3};
#pragma unroll
      for (int j = 0; j < 4; ++j) {
        int P = PaB + j;
        imgB[P * 64 + (chAtt ^ ((P & 7) << 3))] = f2bf(av[j]);
      }
    }
    __syncthreads();

    // ---- phase 6: conv1 ----
#pragma unroll
    for (int nt = 0; nt < 4; ++nt) acc[nt] = zz;
    conv_loop<3, 18, 13>(wsA1, imgB, w, lane, acc);
    __syncthreads();

    // ---- phase 7: LSTM1 + output ----
    float* outrow = out + (size_t)(t * NB + b) * DD;
#pragma unroll
    for (int nt = 0; nt < 4; ++nt) {
      float ig = acc[nt][0] + bi1[0];
      float fg = acc[nt][1] + bi1[1];
      float og = acc[nt][2] + bi1[2];
      float cg = acc[nt][3] + bi1[3];
      float cn = sigm(fg) * c1st[nt] + sigm(ig) * tanh_(cg);
      float hn = sigm(og) * tanh_(cn);
      c1st[nt] = cn;
      imgB[(Pl0 + 24 * nt) * 64 + ((32 + ch) ^ swh)] = f2bf(hn);
      outrow[ch * 64 + nt * 16 + l15] = hn;
    }
    __syncthreads();
  }
}

extern "C" void kernel_launch(void* const* d_in, const int* in_sizes, int n_in,
                              void* d_out, int out_size, void* d_ws, size_t ws_size,
                              hipStream_t stream) {
  const float* x = (const float*)d_in[0];
  const float* W0 = (const float*)d_in[1];
  const float* b0 = (const float*)d_in[2];
  const float* W1 = (const float*)d_in[3];
  const float* b1 = (const float*)d_in[4];
  float* out = (float*)d_out;

  u16* A0 = (u16*)d_ws;                        // 204800 bf16 = 400 KB
  u16* A1 = A0 + 204800;                       // 73728 bf16 = 144 KB
  u16* buf = (u16*)((char*)d_ws + (1 << 20));  // h0-history spill rows (t >= HISTL)

  prep_weights<<<136, 256, 0, stream>>>(W0, W1, A0, A1);
  convlstm_main<<<256, 512, 0, stream>>>(x, b0, b1, A0, A1, buf, out);
}

// Round 4
// 1424.274 us; speedup vs baseline: 1.3956x; 1.0467x over previous
//
#include <hip/hip_runtime.h>

#define TT 40
#define NB 256
#define DD 2048
#define HISTL 28  // history rows kept in LDS; rows >= HISTL live in global ws

typedef __bf16 bf16x8 __attribute__((ext_vector_type(8)));
typedef float f32x4 __attribute__((ext_vector_type(4)));
typedef unsigned short u16;
typedef unsigned int u32;
typedef u16 u16x8 __attribute__((ext_vector_type(8)));
typedef u16 u16x4 __attribute__((ext_vector_type(4)));

__device__ __forceinline__ u16 f2bf(float f) {
  u32 u = __builtin_bit_cast(u32, f);
  return (u16)((u + 0x7fffu + ((u >> 16) & 1u)) >> 16);
}
__device__ __forceinline__ float bf2f(u16 h) {
  return __builtin_bit_cast(float, ((u32)h) << 16);
}
__device__ __forceinline__ bf16x8 asbf(u16x8 v) { return __builtin_bit_cast(bf16x8, v); }

__device__ __forceinline__ float sigm(float x) { return 1.0f / (1.0f + __expf(-x)); }
__device__ __forceinline__ float tanh_(float x) {
  float e = __expf(-2.0f * fabsf(x));
  float t = (1.0f - e) / (1.0f + e);
  return copysignf(t, x);
}

__device__ __forceinline__ f32x4 mfma16(bf16x8 a, bf16x8 b, f32x4 c) {
  return __builtin_amdgcn_mfma_f32_16x16x32_bf16(a, b, c, 0, 0, 0);
}

// ---------------- weight prep: reorder W into A-fragment layout, bf16 ----------------
// A-frag for tile (kt, mt): lane l, elem j holds A[row = mt*16 + (l&15), k = kt*32 + (l>>4)*8 + j]
// row p is PERMUTED oc: oc = (p&3)*32 + ((p>>5)&3)*8 + ((p>>4)&1)*4 + ((p>>2)&3)
// K ordering: k = (ky*KK + kx)*64 + ic
__global__ void prep_weights(const float* __restrict__ W0, const float* __restrict__ W1,
                             u16* __restrict__ A0, u16* __restrict__ A1) {
  int tid = blockIdx.x * 256 + threadIdx.x;
  if (tid < 25600) {  // conv0: 50 ktiles * 8 mtiles * 64 lanes
    int lane = tid & 63;
    int kt = tid >> 9;
    int p = ((tid >> 6) & 7) * 16 + (lane & 15);
    int oc = (p & 3) * 32 + ((p >> 5) & 3) * 8 + ((p >> 4) & 1) * 4 + ((p >> 2) & 3);
    int kb = kt * 32 + (lane >> 4) * 8;
#pragma unroll
    for (int j = 0; j < 8; ++j) {
      int k = kb + j;
      int pos = k >> 6, ic = k & 63;
      int ky = pos / 5, kx = pos - ky * 5;
      A0[tid * 8 + j] = f2bf(W0[((oc * 64 + ic) * 5 + ky) * 5 + kx]);
    }
  } else if (tid < 25600 + 9216) {  // conv1: 18 ktiles * 8 * 64
    int t2 = tid - 25600;
    int lane = t2 & 63;
    int kt = t2 >> 9;
    int p = ((t2 >> 6) & 7) * 16 + (lane & 15);
    int oc = (p & 3) * 32 + ((p >> 5) & 3) * 8 + ((p >> 4) & 1) * 4 + ((p >> 2) & 3);
    int kb = kt * 32 + (lane >> 4) * 8;
#pragma unroll
    for (int j = 0; j < 8; ++j) {
      int k = kb + j;
      int pos = k >> 6, ic = k & 63;
      int ky = pos / 3, kx = pos - ky * 3;
      A1[t2 * 8 + j] = f2bf(W1[((oc * 64 + ic) * 3 + ky) * 3 + kx]);
    }
  }
}

// ---------------- conv inner loop (8 waves: wave w owns M-tile w) ----------------
// img: LDS padded 12x12 image, layout idx = P*64 + (ic ^ ((P&7)<<3)), bf16.
// Depth-4 register prefetch ring on the A-fragments (global, L2-resident).
template <int KK, int NKT, int SKB>
__device__ __forceinline__ void conv_loop(const u16* __restrict__ wsA, const u16* img,
                                          int w, int lane, f32x4 acc[4]) {
  const int ic0v = (lane >> 4) << 3;
  const int pb0 = ((lane & 15) >> 3) * 12 + (lane & 7);
  const bf16x8* A = (const bf16x8*)wsA;
  int aidx = w * 64 + lane;
  bf16x8 a0 = A[aidx];
  bf16x8 a1 = A[aidx + 512];
  bf16x8 a2 = A[aidx + 1024];
  bf16x8 a3 = A[aidx + 1536];
#pragma unroll
  for (int kt = 0; kt < NKT; ++kt) {
    bf16x8 nx = a3;
    if (kt + 4 < NKT) nx = A[aidx + 2048];
    const int pos = kt >> 1, ih = kt & 1;
    const int ky = pos / KK, kx = pos - ky * KK;
    const int Pb = pb0 + (ky * 12 + kx + SKB);
    const int idx = Pb * 64 + ((ic0v ^ ((Pb & 7) << 3)) ^ (ih << 5));
    u16x8 b0v = *(const u16x8*)(img + idx);
    u16x8 b1v = *(const u16x8*)(img + idx + 1536);
    u16x8 b2v = *(const u16x8*)(img + idx + 3072);
    u16x8 b3v = *(const u16x8*)(img + idx + 4608);
    acc[0] = mfma16(a0, asbf(b0v), acc[0]);
    acc[1] = mfma16(a0, asbf(b1v), acc[1]);
    acc[2] = mfma16(a0, asbf(b2v), acc[2]);
    acc[3] = mfma16(a0, asbf(b3v), acc[3]);
    a0 = a1;
    a1 = a2;
    a2 = a3;
    a3 = nx;
    aidx += 512;
  }
}

__device__ __forceinline__ int imin(int a, int b) { return a < b ? a : b; }

// ---------------- main: one batch per block, 512 threads, 3 barriers/step ----------------
__global__ void __launch_bounds__(512, 1)
convlstm_main(const float* __restrict__ x, const float* __restrict__ b0g,
              const float* __restrict__ b1g, const u16* __restrict__ wsA0,
              const u16* __restrict__ wsA1, u16* __restrict__ buf,
              float* __restrict__ out) {
  alignas(16) __shared__ u16 imgA[9216];        // conv0 input: ch0-31 = x_t, ch32-63 = h0
  alignas(16) __shared__ u16 imgB[9216];        // conv1 input: ch0-31 = att, ch32-63 = h1
  alignas(16) __shared__ u16 hist[HISTL * DD];  // h0-history rows 0..HISTL-1 (112 KB)
  alignas(16) __shared__ u16 curr[DD];          // flat_t (current h0 row)
  __shared__ float sdots[64];

  const int tid = threadIdx.x;
  const int b = blockIdx.x;
  const int lane = tid & 63;
  const int w = tid >> 6;
  const int h = lane >> 4;
  const int l15 = lane & 15;

  for (int i = tid; i < 9216; i += 512) {
    imgA[i] = 0;
    imgB[i] = 0;
  }

  float c0st[4] = {};
  float c1st[4] = {};
  float bi0[4], bi1[4];
  const int ch = ((w >> 1) & 3) * 8 + (w & 1) * 4 + h;  // this lane's conv-output channel
#pragma unroll
  for (int j = 0; j < 4; ++j) {
    bi0[j] = b0g[j * 32 + ch];
    bi1[j] = b1g[j * 32 + ch];
  }

  const int Pldx = ((lane >> 3) + 2) * 12 + (lane & 7) + 2;  // x-load pixel (px = lane)
  const int swx = (Pldx & 7) << 3;
  const int Pl0 = ((l15 >> 3) + 2) * 12 + (l15 & 7) + 2;  // h-write pixel base
  const int swh = (Pl0 & 7) << 3;
  const int e4 = tid * 4;              // att: this thread's 4 d-elems
  const int chAtt = tid >> 4;          // att write channel
  const int pix0 = (tid & 15) * 4;     // att write pixel base
  const int PaB = ((pix0 >> 3) + 2) * 12 + (pix0 & 7) + 2;

  // prologue: stage x(0) directly, preload xr = x(1)
  float xr[4];
  {
    const float* xp0 = x + (size_t)b * DD;
#pragma unroll
    for (int i = 0; i < 4; ++i) {
      int c = i * 8 + w;
      imgA[Pldx * 64 + (c ^ swx)] = f2bf(__builtin_nontemporal_load(xp0 + c * 64 + lane));
    }
    const float* xp1 = x + (size_t)(NB + b) * DD;
#pragma unroll
    for (int i = 0; i < 4; ++i)
      xr[i] = __builtin_nontemporal_load(xp1 + (i * 8 + w) * 64 + lane);
  }

  u16 hb[4];   // h0(t) pending deferred write to imgA.h
  u16 h1b[4];  // h1(t-1) pending deferred write to imgB.h

  __syncthreads();

  for (int t = 0; t < TT; ++t) {
    // ---- conv0 + LSTM0 (reads imgA; writes curr/hist/buf + regs only) ----
    f32x4 acc[4];
    f32x4 zz = {0.f, 0.f, 0.f, 0.f};
#pragma unroll
    for (int nt = 0; nt < 4; ++nt) acc[nt] = zz;
    conv_loop<5, 50, 0>(wsA0, imgA, w, lane, acc);

    u16* bufrow = buf + (size_t)(t * NB + b) * DD;  // used only when t >= HISTL
#pragma unroll
    for (int nt = 0; nt < 4; ++nt) {
      float ig = acc[nt][0] + bi0[0];
      float fg = acc[nt][1] + bi0[1];
      float og = acc[nt][2] + bi0[2];
      float cg = acc[nt][3] + bi0[3];
      float cn = sigm(fg) * c0st[nt] + sigm(ig) * tanh_(cg);
      float hn = sigm(og) * tanh_(cn);
      c0st[nt] = cn;
      u16 hv = f2bf(hn);
      hb[nt] = hv;
      int d = ch * 64 + nt * 16 + l15;
      curr[d] = hv;
      if (t < HISTL)
        hist[t * DD + d] = hv;
      else
        bufrow[d] = hv;
    }
    __syncthreads();  // ===== barrier A: curr/hist row t visible =====

    // deferred writes (safe: conv0(t) and conv1(t-1) readers are all past)
#pragma unroll
    for (int nt = 0; nt < 4; ++nt)
      imgA[(Pl0 + 24 * nt) * 64 + ((32 + ch) ^ swh)] = hb[nt];
    if (t > 0) {
#pragma unroll
      for (int nt = 0; nt < 4; ++nt)
        imgB[(Pl0 + 24 * nt) * 64 + ((32 + ch) ^ swh)] = h1b[nt];
    }
    if (t + 1 < TT) {  // stage x(t+1) from regs
#pragma unroll
      for (int i = 0; i < 4; ++i) {
        int c = i * 8 + w;
        imgA[Pldx * 64 + (c ^ swx)] = f2bf(xr[i]);
      }
    }
    if (t + 2 < TT) {  // issue x(t+2) loads (drained at barrier B; covered by dots)
      const float* xp = x + (size_t)((t + 2) * NB + b) * DD;
#pragma unroll
      for (int i = 0; i < 4; ++i)
        xr[i] = __builtin_nontemporal_load(xp + (i * 8 + w) * 64 + lane);
    }

    // ---- dots[t'] = flat . hist[t'] for t' <= t (wave-striped tp) ----
    {
      u16x8 fv[4];  // flat_t from LDS curr
      {
        const u16x8* rowT = (const u16x8*)curr;
#pragma unroll
        for (int i = 0; i < 4; ++i) fv[i] = rowT[i * 64 + lane];
      }
      int tp = w;
      for (; tp <= t && tp < HISTL; tp += 8) {  // LDS rows
        const u16x8* rowP = (const u16x8*)&hist[tp * DD];
        u16x8 p0 = rowP[lane], p1 = rowP[64 + lane], p2 = rowP[128 + lane], p3 = rowP[192 + lane];
        float s0 = 0.f, s1 = 0.f, s2 = 0.f, s3 = 0.f;
#pragma unroll
        for (int j = 0; j < 8; ++j) {
          s0 += bf2f(fv[0][j]) * bf2f(p0[j]);
          s1 += bf2f(fv[1][j]) * bf2f(p1[j]);
          s2 += bf2f(fv[2][j]) * bf2f(p2[j]);
          s3 += bf2f(fv[3][j]) * bf2f(p3[j]);
        }
        float s = (s0 + s1) + (s2 + s3);
#pragma unroll
        for (int off = 32; off; off >>= 1) s += __shfl_xor(s, off, 64);
        if (lane == 0) sdots[tp] = s;
      }
      for (; tp < t; tp += 8) {  // global rows HISTL..t-1
        const u16x8* rowP = (const u16x8*)(buf + (size_t)(tp * NB + b) * DD);
        u16x8 p0 = rowP[lane], p1 = rowP[64 + lane], p2 = rowP[128 + lane], p3 = rowP[192 + lane];
        float s0 = 0.f, s1 = 0.f, s2 = 0.f, s3 = 0.f;
#pragma unroll
        for (int j = 0; j < 8; ++j) {
          s0 += bf2f(fv[0][j]) * bf2f(p0[j]);
          s1 += bf2f(fv[1][j]) * bf2f(p1[j]);
          s2 += bf2f(fv[2][j]) * bf2f(p2[j]);
          s3 += bf2f(fv[3][j]) * bf2f(p3[j]);
        }
        float s = (s0 + s1) + (s2 + s3);
#pragma unroll
        for (int off = 32; off; off >>= 1) s += __shfl_xor(s, off, 64);
        if (lane == 0) sdots[tp] = s;
      }
      if (tp == t) {  // row t self-dot (only reached when t >= HISTL)
        float s0 = 0.f, s1 = 0.f, s2 = 0.f, s3 = 0.f;
#pragma unroll
        for (int j = 0; j < 8; ++j) {
          s0 += bf2f(fv[0][j]) * bf2f(fv[0][j]);
          s1 += bf2f(fv[1][j]) * bf2f(fv[1][j]);
          s2 += bf2f(fv[2][j]) * bf2f(fv[2][j]);
          s3 += bf2f(fv[3][j]) * bf2f(fv[3][j]);
        }
        float s = (s0 + s1) + (s2 + s3);
#pragma unroll
        for (int off = 32; off; off >>= 1) s += __shfl_xor(s, off, 64);
        if (lane == 0) sdots[tp] = s;
      }
    }
    __syncthreads();  // ===== barrier B: sdots complete =====

    // ---- softmax over t'<=t, redundantly in EVERY wave; weights stay in regs ----
    float myw;  // this lane's softmax weight for tp = lane
    {
      float v = (lane <= t) ? sdots[lane] : -3.0e38f;
      float m = v;
#pragma unroll
      for (int off = 32; off; off >>= 1) m = fmaxf(m, __shfl_xor(m, off, 64));
      float e = (lane <= t) ? __expf(v - m) : 0.f;
      float ss = e;
#pragma unroll
      for (int off = 32; off; off >>= 1) ss += __shfl_xor(ss, off, 64);
      myw = e / ss;
    }

    // ---- att = sum_t' w[t'] * hist[t'] -> imgB channels 0..31 ----
    {
      float av0 = 0.f, av1 = 0.f, av2 = 0.f, av3 = 0.f;
      const int lim = imin(t, HISTL);  // LDS rows [0, lim); row t handled from curr
      int tp = 0;
      for (; tp + 1 < lim; tp += 2) {
        float wa = __shfl(myw, tp, 64), wb = __shfl(myw, tp + 1, 64);
        u16x4 va = *(const u16x4*)&hist[tp * DD + e4];
        u16x4 vb = *(const u16x4*)&hist[(tp + 1) * DD + e4];
        av0 = fmaf(wa, bf2f(va[0]), av0);
        av1 = fmaf(wa, bf2f(va[1]), av1);
        av2 = fmaf(wa, bf2f(va[2]), av2);
        av3 = fmaf(wa, bf2f(va[3]), av3);
        av0 = fmaf(wb, bf2f(vb[0]), av0);
        av1 = fmaf(wb, bf2f(vb[1]), av1);
        av2 = fmaf(wb, bf2f(vb[2]), av2);
        av3 = fmaf(wb, bf2f(vb[3]), av3);
      }
      if (tp < lim) {
        float wa = __shfl(myw, tp, 64);
        u16x4 va = *(const u16x4*)&hist[tp * DD + e4];
        av0 = fmaf(wa, bf2f(va[0]), av0);
        av1 = fmaf(wa, bf2f(va[1]), av1);
        av2 = fmaf(wa, bf2f(va[2]), av2);
        av3 = fmaf(wa, bf2f(va[3]), av3);
      }
      tp = HISTL;
      for (; tp + 1 < t; tp += 2) {
        float wa = __shfl(myw, tp, 64), wb = __shfl(myw, tp + 1, 64);
        u16x4 va = *(const u16x4*)(buf + (size_t)(tp * NB + b) * DD + e4);
        u16x4 vb = *(const u16x4*)(buf + (size_t)((tp + 1) * NB + b) * DD + e4);
        av0 = fmaf(wa, bf2f(va[0]), av0);
        av1 = fmaf(wa, bf2f(va[1]), av1);
        av2 = fmaf(wa, bf2f(va[2]), av2);
        av3 = fmaf(wa, bf2f(va[3]), av3);
        av0 = fmaf(wb, bf2f(vb[0]), av0);
        av1 = fmaf(wb, bf2f(vb[1]), av1);
        av2 = fmaf(wb, bf2f(vb[2]), av2);
        av3 = fmaf(wb, bf2f(vb[3]), av3);
      }
      if (tp < t) {
        float wa = __shfl(myw, tp, 64);
        u16x4 va = *(const u16x4*)(buf + (size_t)(tp * NB + b) * DD + e4);
        av0 = fmaf(wa, bf2f(va[0]), av0);
        av1 = fmaf(wa, bf2f(va[1]), av1);
        av2 = fmaf(wa, bf2f(va[2]), av2);
        av3 = fmaf(wa, bf2f(va[3]), av3);
      }
      {  // row t from curr
        float wa = __shfl(myw, t, 64);
        u16x4 va = *(const u16x4*)&curr[e4];
        av0 = fmaf(wa, bf2f(va[0]), av0);
        av1 = fmaf(wa, bf2f(va[1]), av1);
        av2 = fmaf(wa, bf2f(va[2]), av2);
        av3 = fmaf(wa, bf2f(va[3]), av3);
      }
      float av[4] = {av0, av1, av2, av3};
#pragma unroll
      for (int j = 0; j < 4; ++j) {
        int P = PaB + j;
        imgB[P * 64 + (chAtt ^ ((P & 7) << 3))] = f2bf(av[j]);
      }
    }
    __syncthreads();  // ===== barrier C: imgB.att + deferred h-halves visible =====

    // ---- conv1 + LSTM1 (reads imgB; writes out + regs only) ----
#pragma unroll
    for (int nt = 0; nt < 4; ++nt) acc[nt] = zz;
    conv_loop<3, 18, 13>(wsA1, imgB, w, lane, acc);

    float* outrow = out + (size_t)(t * NB + b) * DD;
#pragma unroll
    for (int nt = 0; nt < 4; ++nt) {
      float ig = acc[nt][0] + bi1[0];
      float fg = acc[nt][1] + bi1[1];
      float og = acc[nt][2] + bi1[2];
      float cg = acc[nt][3] + bi1[3];
      float cn = sigm(fg) * c1st[nt] + sigm(ig) * tanh_(cg);
      float hn = sigm(og) * tanh_(cn);
      c1st[nt] = cn;
      h1b[nt] = f2bf(hn);  // deferred to after barrier A of t+1
      __builtin_nontemporal_store(hn, outrow + ch * 64 + nt * 16 + l15);
    }
    // no end-of-loop barrier: next conv0 reads imgA only (stable since barrier B)
  }
}

extern "C" void kernel_launch(void* const* d_in, const int* in_sizes, int n_in,
                              void* d_out, int out_size, void* d_ws, size_t ws_size,
                              hipStream_t stream) {
  const float* x = (const float*)d_in[0];
  const float* W0 = (const float*)d_in[1];
  const float* b0 = (const float*)d_in[2];
  const float* W1 = (const float*)d_in[3];
  const float* b1 = (const float*)d_in[4];
  float* out = (float*)d_out;

  u16* A0 = (u16*)d_ws;                        // 204800 bf16 = 400 KB
  u16* A1 = A0 + 204800;                       // 73728 bf16 = 144 KB
  u16* buf = (u16*)((char*)d_ws + (1 << 20));  // h0-history spill rows (t >= HISTL)

  prep_weights<<<136, 256, 0, stream>>>(W0, W1, A0, A1);
  convlstm_main<<<256, 512, 0, stream>>>(x, b0, b1, A0, A1, buf, out);
}

// Round 5
// 1313.133 us; speedup vs baseline: 1.5137x; 1.0846x over previous
//
#include <hip/hip_runtime.h>

#define TT 40
#define NB 256
#define DD 2048
#define HISTL 28  // history rows kept in LDS; rows >= HISTL live in global ws

typedef __bf16 bf16x8 __attribute__((ext_vector_type(8)));
typedef float f32x4 __attribute__((ext_vector_type(4)));
typedef unsigned short u16;
typedef unsigned int u32;
typedef u16 u16x8 __attribute__((ext_vector_type(8)));
typedef u16 u16x4 __attribute__((ext_vector_type(4)));

__device__ __forceinline__ u16 f2bf(float f) {
  u32 u = __builtin_bit_cast(u32, f);
  return (u16)((u + 0x7fffu + ((u >> 16) & 1u)) >> 16);
}
__device__ __forceinline__ float bf2f(u16 h) {
  return __builtin_bit_cast(float, ((u32)h) << 16);
}
__device__ __forceinline__ bf16x8 asbf(u16x8 v) { return __builtin_bit_cast(bf16x8, v); }

__device__ __forceinline__ float sigm(float x) { return 1.0f / (1.0f + __expf(-x)); }
__device__ __forceinline__ float tanh_(float x) {
  float e = __expf(-2.0f * fabsf(x));
  float t = (1.0f - e) / (1.0f + e);
  return copysignf(t, x);
}

__device__ __forceinline__ f32x4 mfma16(bf16x8 a, bf16x8 b, f32x4 c) {
  return __builtin_amdgcn_mfma_f32_16x16x32_bf16(a, b, c, 0, 0, 0);
}

__device__ __forceinline__ int imin(int a, int b) { return a < b ? a : b; }

// ---------------- weight prep: reorder W into A-fragment layout, bf16 ----------------
// A-frag for tile (kt, mt): lane l, elem j holds A[row = mt*16 + (l&15), k = kt*32 + (l>>4)*8 + j]
// row p is PERMUTED oc: oc = (p&3)*32 + ((p>>5)&3)*8 + ((p>>4)&1)*4 + ((p>>2)&3)
// K ordering: k = (ky*KK + kx)*64 + ic
__global__ void prep_weights(const float* __restrict__ W0, const float* __restrict__ W1,
                             u16* __restrict__ A0, u16* __restrict__ A1) {
  int tid = blockIdx.x * 256 + threadIdx.x;
  if (tid < 25600) {  // conv0: 50 ktiles * 8 mtiles * 64 lanes
    int lane = tid & 63;
    int kt = tid >> 9;
    int p = ((tid >> 6) & 7) * 16 + (lane & 15);
    int oc = (p & 3) * 32 + ((p >> 5) & 3) * 8 + ((p >> 4) & 1) * 4 + ((p >> 2) & 3);
    int kb = kt * 32 + (lane >> 4) * 8;
#pragma unroll
    for (int j = 0; j < 8; ++j) {
      int k = kb + j;
      int pos = k >> 6, ic = k & 63;
      int ky = pos / 5, kx = pos - ky * 5;
      A0[tid * 8 + j] = f2bf(W0[((oc * 64 + ic) * 5 + ky) * 5 + kx]);
    }
  } else if (tid < 25600 + 9216) {  // conv1: 18 ktiles * 8 * 64
    int t2 = tid - 25600;
    int lane = t2 & 63;
    int kt = t2 >> 9;
    int p = ((t2 >> 6) & 7) * 16 + (lane & 15);
    int oc = (p & 3) * 32 + ((p >> 5) & 3) * 8 + ((p >> 4) & 1) * 4 + ((p >> 2) & 3);
    int kb = kt * 32 + (lane >> 4) * 8;
#pragma unroll
    for (int j = 0; j < 8; ++j) {
      int k = kb + j;
      int pos = k >> 6, ic = k & 63;
      int ky = pos / 3, kx = pos - ky * 3;
      A1[t2 * 8 + j] = f2bf(W1[((oc * 64 + ic) * 3 + ky) * 3 + kx]);
    }
  }
}

// ---------------- conv inner loop: 4 waves, wave wg owns M-tiles {2wg, 2wg+1} ----------------
// img: LDS padded 12x12 image, layout idx = P*64 + (ic ^ ((P&7)<<3)), bf16.
// DEPTH-deep register prefetch ring (modular slots, compile-time under full unroll).
template <int KK, int NKT, int SKB, int DEPTH>
__device__ __forceinline__ void conv_loop2(const u16* __restrict__ wsA, const u16* img,
                                           int wg, int lane, f32x4 acc[2][4]) {
  const int ic0v = (lane >> 4) << 3;
  const int pb0 = ((lane & 15) >> 3) * 12 + (lane & 7);
  const bf16x8* A = (const bf16x8*)wsA;
  const int aidx = 2 * wg * 64 + lane;
  bf16x8 r0[DEPTH], r1[DEPTH];
#pragma unroll
  for (int i = 0; i < DEPTH; ++i) {
    r0[i] = A[aidx + i * 512];
    r1[i] = A[aidx + i * 512 + 64];
  }
#pragma unroll
  for (int kt = 0; kt < NKT; ++kt) {
    const int slot = kt % DEPTH;
    const bf16x8 c0 = r0[slot];
    const bf16x8 c1 = r1[slot];
    if (kt + DEPTH < NKT) {
      r0[slot] = A[aidx + (kt + DEPTH) * 512];
      r1[slot] = A[aidx + (kt + DEPTH) * 512 + 64];
    }
    const int pos = kt >> 1, ih = kt & 1;
    const int ky = pos / KK, kx = pos - ky * KK;
    const int Pb = pb0 + (ky * 12 + kx + SKB);
    const int idx = Pb * 64 + ((ic0v ^ ((Pb & 7) << 3)) ^ (ih << 5));
    u16x8 b0v = *(const u16x8*)(img + idx);
    u16x8 b1v = *(const u16x8*)(img + idx + 1536);
    u16x8 b2v = *(const u16x8*)(img + idx + 3072);
    u16x8 b3v = *(const u16x8*)(img + idx + 4608);
    acc[0][0] = mfma16(c0, asbf(b0v), acc[0][0]);
    acc[1][0] = mfma16(c1, asbf(b0v), acc[1][0]);
    acc[0][1] = mfma16(c0, asbf(b1v), acc[0][1]);
    acc[1][1] = mfma16(c1, asbf(b1v), acc[1][1]);
    acc[0][2] = mfma16(c0, asbf(b2v), acc[0][2]);
    acc[1][2] = mfma16(c1, asbf(b2v), acc[1][2]);
    acc[0][3] = mfma16(c0, asbf(b3v), acc[0][3]);
    acc[1][3] = mfma16(c1, asbf(b3v), acc[1][3]);
  }
}

// ---------------- main: one batch per block; waves 0-3 = conv0 pipe (A), 4-7 = attn+conv1 (B) ----
// Software pipeline over s = 0..TT+1:
//   phase1: A: conv0(s)          B: conv1(s-2), dots(s-1)
//   phase2: A: LSTM0(s)+stage    B: LSTM1(s-2)+out, softmax+att(s-1)
// History rows stored PERMUTED: slot = ch*64 + l15*4 + nt  (pixel = nt*16 + l15)
__global__ void __launch_bounds__(512, 1)
convlstm_main(const float* __restrict__ x, const float* __restrict__ b0g,
              const float* __restrict__ b1g, const u16* __restrict__ wsA0,
              const u16* __restrict__ wsA1, u16* __restrict__ buf,
              float* __restrict__ out) {
  alignas(16) __shared__ u16 imgA[9216];        // conv0 input: ch0-31 = x_t, ch32-63 = h0
  alignas(16) __shared__ u16 imgB[9216];        // conv1 input: ch0-31 = att, ch32-63 = h1
  alignas(16) __shared__ u16 hist[HISTL * DD];  // h0-history rows 0..HISTL-1 (112 KB, permuted)
  alignas(16) __shared__ u16 curr[2 * DD];      // h0 row double-buffer (permuted)
  __shared__ float sdots[64];

  const int tid = threadIdx.x;
  const int b = blockIdx.x;
  const int lane = tid & 63;
  const int w = tid >> 6;
  const bool isA = (w < 4);
  const int wg = w & 3;
  const int h = lane >> 4;
  const int l15 = lane & 15;
  const int ch0 = 8 * wg + h;  // + 4*mi

  for (int i = tid; i < 9216; i += 512) {
    imgA[i] = 0;
    imgB[i] = 0;
  }

  float cst[2][4] = {};  // A: c0 state, B: c1 state
  float bi[2][4];
  {
    const float* bg = isA ? b0g : b1g;
#pragma unroll
    for (int mi = 0; mi < 2; ++mi)
#pragma unroll
      for (int j = 0; j < 4; ++j) bi[mi][j] = bg[j * 32 + ch0 + 4 * mi];
  }

  // A-side addressing
  const int Pldx = ((lane >> 3) + 2) * 12 + (lane & 7) + 2;  // x-load pixel (px = lane)
  const int swx = (Pldx & 7) << 3;
  const int Pl0 = ((l15 >> 3) + 2) * 12 + (l15 & 7) + 2;  // h-write pixel base
  const int swh = (Pl0 & 7) << 3;
  // B-side addressing
  const int bt = tid & 255;  // B thread id 0..255
  const int e8 = bt * 8;     // this thread's 8 slots of a history row
  const int chB = bt >> 3;   // att output channel

  __syncthreads();  // zero-init visible before x(0) staging overwrites interior

  float xr[8];
  if (isA) {
    const float* xp0 = x + (size_t)b * DD;
#pragma unroll
    for (int i = 0; i < 8; ++i) {
      int c = i * 4 + wg;
      imgA[Pldx * 64 + (c ^ swx)] = f2bf(xp0[c * 64 + lane]);
    }
    const float* xp1 = x + (size_t)(NB + b) * DD;
#pragma unroll
    for (int i = 0; i < 8; ++i) xr[i] = xp1[(i * 4 + wg) * 64 + lane];
  }

  __syncthreads();

  for (int s = 0; s <= TT + 1; ++s) {
    f32x4 acc[2][4];
    f32x4 zz = {0.f, 0.f, 0.f, 0.f};
#pragma unroll
    for (int mi = 0; mi < 2; ++mi)
#pragma unroll
      for (int nt = 0; nt < 4; ++nt) acc[mi][nt] = zz;

    // ================= phase 1 =================
    if (isA) {
      if (s < TT) conv_loop2<5, 50, 0, 8>(wsA0, imgA, wg, lane, acc);
    } else {
      if (s >= 2) conv_loop2<3, 18, 13, 6>(wsA1, imgB, wg, lane, acc);
      const int t1 = s - 1;
      if (t1 >= 0 && t1 < TT) {  // dots(t1), rows striped over B's 4 waves
        u16x8 fv[4];
        const u16x8* rowT = (const u16x8*)&curr[(t1 & 1) * DD];
#pragma unroll
        for (int i = 0; i < 4; ++i) fv[i] = rowT[i * 64 + lane];
        int tp = wg;
        for (; tp <= t1 && tp < HISTL; tp += 4) {  // LDS rows
          const u16x8* rowP = (const u16x8*)&hist[tp * DD];
          u16x8 p0 = rowP[lane], p1 = rowP[64 + lane], p2 = rowP[128 + lane],
                p3 = rowP[192 + lane];
          float d0 = 0.f, d1 = 0.f, d2 = 0.f, d3 = 0.f;
#pragma unroll
          for (int j = 0; j < 8; ++j) {
            d0 += bf2f(fv[0][j]) * bf2f(p0[j]);
            d1 += bf2f(fv[1][j]) * bf2f(p1[j]);
            d2 += bf2f(fv[2][j]) * bf2f(p2[j]);
            d3 += bf2f(fv[3][j]) * bf2f(p3[j]);
          }
          float dsum = (d0 + d1) + (d2 + d3);
#pragma unroll
          for (int off = 32; off; off >>= 1) dsum += __shfl_xor(dsum, off, 64);
          if (lane == 0) sdots[tp] = dsum;
        }
        for (; tp < t1; tp += 4) {  // global rows HISTL..t1-1
          const u16x8* rowP = (const u16x8*)(buf + (size_t)(tp * NB + b) * DD);
          u16x8 p0 = rowP[lane], p1 = rowP[64 + lane], p2 = rowP[128 + lane],
                p3 = rowP[192 + lane];
          float d0 = 0.f, d1 = 0.f, d2 = 0.f, d3 = 0.f;
#pragma unroll
          for (int j = 0; j < 8; ++j) {
            d0 += bf2f(fv[0][j]) * bf2f(p0[j]);
            d1 += bf2f(fv[1][j]) * bf2f(p1[j]);
            d2 += bf2f(fv[2][j]) * bf2f(p2[j]);
            d3 += bf2f(fv[3][j]) * bf2f(p3[j]);
          }
          float dsum = (d0 + d1) + (d2 + d3);
#pragma unroll
          for (int off = 32; off; off >>= 1) dsum += __shfl_xor(dsum, off, 64);
          if (lane == 0) sdots[tp] = dsum;
        }
        if (tp == t1) {  // self-dot (only reached when t1 >= HISTL)
          float d0 = 0.f, d1 = 0.f, d2 = 0.f, d3 = 0.f;
#pragma unroll
          for (int j = 0; j < 8; ++j) {
            d0 += bf2f(fv[0][j]) * bf2f(fv[0][j]);
            d1 += bf2f(fv[1][j]) * bf2f(fv[1][j]);
            d2 += bf2f(fv[2][j]) * bf2f(fv[2][j]);
            d3 += bf2f(fv[3][j]) * bf2f(fv[3][j]);
          }
          float dsum = (d0 + d1) + (d2 + d3);
#pragma unroll
          for (int off = 32; off; off >>= 1) dsum += __shfl_xor(dsum, off, 64);
          if (lane == 0) sdots[tp] = dsum;
        }
      }
    }
    __syncthreads();  // ===== barrier 1 =====

    // ================= phase 2 =================
    if (isA) {
      if (s < TT) {
        u16* bufrow = buf + (size_t)(s * NB + b) * DD;
        u16* crow = &curr[(s & 1) * DD];
#pragma unroll
        for (int mi = 0; mi < 2; ++mi) {
          const int chm = ch0 + 4 * mi;
          u16x4 hv4;
#pragma unroll
          for (int nt = 0; nt < 4; ++nt) {
            float ig = acc[mi][nt][0] + bi[mi][0];
            float fg = acc[mi][nt][1] + bi[mi][1];
            float og = acc[mi][nt][2] + bi[mi][2];
            float cg = acc[mi][nt][3] + bi[mi][3];
            float cn = sigm(fg) * cst[mi][nt] + sigm(ig) * tanh_(cg);
            float hn = sigm(og) * tanh_(cn);
            cst[mi][nt] = cn;
            u16 hv = f2bf(hn);
            hv4[nt] = hv;
            imgA[(Pl0 + 24 * nt) * 64 + ((32 + chm) ^ swh)] = hv;
          }
          const int dbase = chm * 64 + l15 * 4;  // permuted row layout
          *(u16x4*)&crow[dbase] = hv4;
          if (s < HISTL)
            *(u16x4*)&hist[s * DD + dbase] = hv4;
          else
            *(u16x4*)(bufrow + dbase) = hv4;
        }
        if (s + 1 < TT) {  // stage x(s+1) from regs
#pragma unroll
          for (int i = 0; i < 8; ++i) {
            int c = i * 4 + wg;
            imgA[Pldx * 64 + (c ^ swx)] = f2bf(xr[i]);
          }
        }
        if (s + 2 < TT) {  // issue x(s+2) loads
          const float* xp = x + (size_t)((s + 2) * NB + b) * DD;
#pragma unroll
          for (int i = 0; i < 8; ++i) xr[i] = xp[(i * 4 + wg) * 64 + lane];
        }
      }
    } else {
      const int t2 = s - 2;
      if (t2 >= 0) {  // LSTM1(t2) + out
        float* outrow = out + (size_t)(t2 * NB + b) * DD;
#pragma unroll
        for (int mi = 0; mi < 2; ++mi) {
          const int chm = ch0 + 4 * mi;
#pragma unroll
          for (int nt = 0; nt < 4; ++nt) {
            float ig = acc[mi][nt][0] + bi[mi][0];
            float fg = acc[mi][nt][1] + bi[mi][1];
            float og = acc[mi][nt][2] + bi[mi][2];
            float cg = acc[mi][nt][3] + bi[mi][3];
            float cn = sigm(fg) * cst[mi][nt] + sigm(ig) * tanh_(cg);
            float hn = sigm(og) * tanh_(cn);
            cst[mi][nt] = cn;
            imgB[(Pl0 + 24 * nt) * 64 + ((32 + chm) ^ swh)] = f2bf(hn);
            outrow[chm * 64 + nt * 16 + l15] = hn;
          }
        }
      }
      const int t1 = s - 1;
      if (t1 >= 0 && t1 < TT) {  // softmax + att(t1)
        float myw;
        {
          float v = (lane <= t1) ? sdots[lane] : -3.0e38f;
          float m = v;
#pragma unroll
          for (int off = 32; off; off >>= 1) m = fmaxf(m, __shfl_xor(m, off, 64));
          float e = (lane <= t1) ? __expf(v - m) : 0.f;
          float ss = e;
#pragma unroll
          for (int off = 32; off; off >>= 1) ss += __shfl_xor(ss, off, 64);
          myw = e / ss;
        }
        float av[8] = {0.f, 0.f, 0.f, 0.f, 0.f, 0.f, 0.f, 0.f};
        const int lim = imin(t1, HISTL);
        int tp = 0;
        for (; tp < lim; ++tp) {  // LDS rows
          float wt = __shfl(myw, tp, 64);
          u16x8 v = *(const u16x8*)&hist[tp * DD + e8];
#pragma unroll
          for (int j = 0; j < 8; ++j) av[j] = fmaf(wt, bf2f(v[j]), av[j]);
        }
        for (tp = HISTL; tp < t1; ++tp) {  // global rows
          float wt = __shfl(myw, tp, 64);
          u16x8 v = *(const u16x8*)(buf + (size_t)(tp * NB + b) * DD + e8);
#pragma unroll
          for (int j = 0; j < 8; ++j) av[j] = fmaf(wt, bf2f(v[j]), av[j]);
        }
        {  // row t1 from curr
          float wt = __shfl(myw, t1, 64);
          u16x8 v = *(const u16x8*)&curr[(t1 & 1) * DD + e8];
#pragma unroll
          for (int j = 0; j < 8; ++j) av[j] = fmaf(wt, bf2f(v[j]), av[j]);
        }
#pragma unroll
        for (int j = 0; j < 8; ++j) {  // un-permute: slot -> (ch, pixel) -> imgB
          const int pixel = (j & 3) * 16 + (bt & 7) * 2 + (j >> 2);
          const int P = ((pixel >> 3) + 2) * 12 + (pixel & 7) + 2;
          imgB[P * 64 + (chB ^ ((P & 7) << 3))] = f2bf(av[j]);
        }
      }
    }
    __syncthreads();  // ===== barrier 2 =====
  }
}

extern "C" void kernel_launch(void* const* d_in, const int* in_sizes, int n_in,
                              void* d_out, int out_size, void* d_ws, size_t ws_size,
                              hipStream_t stream) {
  const float* x = (const float*)d_in[0];
  const float* W0 = (const float*)d_in[1];
  const float* b0 = (const float*)d_in[2];
  const float* W1 = (const float*)d_in[3];
  const float* b1 = (const float*)d_in[4];
  float* out = (float*)d_out;

  u16* A0 = (u16*)d_ws;                        // 204800 bf16 = 400 KB
  u16* A1 = A0 + 204800;                       // 73728 bf16 = 144 KB
  u16* buf = (u16*)((char*)d_ws + (1 << 20));  // h0-history spill rows (t >= HISTL), permuted

  prep_weights<<<136, 256, 0, stream>>>(W0, W1, A0, A1);
  convlstm_main<<<256, 512, 0, stream>>>(x, b0, b1, A0, A1, buf, out);
}